// Round 13
// baseline (144.215 us; speedup 1.0000x reference)
//
#include <hip/hip_runtime.h>

// Problem constants: H1=15, H2=60, H3=20, T=15, IN=1
#define HH   15
#define TT   15
#define NH2  60
#define NH3  20

#define LOG2E 1.44269504088896340736f
#define L2E2  2.88539008177792680736f   // 2*LOG2E

typedef _Float16 f16x8 __attribute__((ext_vector_type(8)));
typedef float    f32x4 __attribute__((ext_vector_type(4)));

// ws layout (dwords): frag f in 0..7 at [f*256 + lane*4 + d]; v[15] at 2048; cb at 2063
#define WS_V  2048
#define WS_CB 2063

__device__ __forceinline__ float fast_rcp(float x)  { return __builtin_amdgcn_rcpf(x); }
__device__ __forceinline__ float fast_exp2(float x) { return __builtin_amdgcn_exp2f(x); }

// ---------------- prep: pack B-fragments for v_mfma_f32_16x16x32_f16 ----------------
// SHARED-A-BUFFER k-layout (row = one batch element's A-row, 32 used halves):
//   k0-14: h1 | k15: x | k16: 1.0 | k17-31: h2
// B-frag: lane l holds B[k=(l>>4)*8+j][col=l&15]. Tiles n={i,f,g,o}, row r=n*15+u.
//   L1 (frags 0-3): k<15: Whh0[r][k]; k==15: Wih0[r]; k==16: bias0[r]; k17-31: 0
//   L2 (frags 4-7): k<15: Wih1[r][k]; k==15: 0;       k==16: bias1[r]; k17-31: Whh1[r][k-17]
// scaled by LOG2E (2*LOG2E for g-gate tile n==2).
__global__ void lstm_prep(const float* __restrict__ Wih0, const float* __restrict__ Whh0,
                          const float* __restrict__ bih0, const float* __restrict__ bhh0,
                          const float* __restrict__ Wih1, const float* __restrict__ Whh1,
                          const float* __restrict__ bih1, const float* __restrict__ bhh1,
                          const float* __restrict__ W1, const float* __restrict__ b1,
                          const float* __restrict__ W2, const float* __restrict__ b2,
                          const float* __restrict__ W3, const float* __restrict__ b3,
                          float* __restrict__ wsf)
{
    const int tid = threadIdx.x;
    unsigned* wsu = (unsigned*)wsf;

    {   // one thread per (frag, lane)
        const int f = tid >> 6, l = tid & 63;
        const int n = f & 3;
        const bool isL2 = (f >= 4);
        const int u = l & 15, g = l >> 4;
        const float sc = (n == 2) ? L2E2 : LOG2E;
        const int r = n * 15 + (u < 15 ? u : 0);
        float vals[8];
        #pragma unroll
        for (int j = 0; j < 8; ++j) {
            const int k = g * 8 + j;
            float v = 0.0f;
            if (u < 15) {
                if (!isL2) {
                    if (k < 15)       v = Whh0[r * 15 + k];
                    else if (k == 15) v = Wih0[r];
                    else if (k == 16) v = bih0[r] + bhh0[r];
                    // k17-31: 0 (h2 region masked for L1)
                } else {
                    if (k < 15)       v = Wih1[r * 15 + k];
                    else if (k == 16) v = bih1[r] + bhh1[r];
                    else if (k >= 17) v = Whh1[r * 15 + (k - 17)];
                    // k15 (x slot): 0 for L2
                }
            }
            vals[j] = v * sc;
        }
        #pragma unroll
        for (int d = 0; d < 4; ++d) {
            union { _Float16 h[2]; unsigned u32; } p;
            p.h[0] = (_Float16)vals[2 * d];
            p.h[1] = (_Float16)vals[2 * d + 1];
            wsu[f * 256 + l * 4 + d] = p.u32;
        }
    }

    // collapsed affine head: u = W3@W2 (60), v = u@W1 (15), cb scalar
    __shared__ float sU[NH2];
    if (tid < NH2) {
        float ua = 0.0f;
        #pragma unroll
        for (int k = 0; k < NH3; ++k) ua = fmaf(W3[k], W2[k * NH2 + tid], ua);
        sU[tid] = ua;
    }
    __syncthreads();
    if (tid < TT) {
        float v = 0.0f;
        for (int j = 0; j < NH2; ++j) v = fmaf(sU[j], W1[j * HH + tid], v);
        wsf[WS_V + tid] = v;
    }
    if (tid == 0) {
        float c = b3[0];
        for (int k = 0; k < NH3; ++k) c = fmaf(W3[k], b2[k], c);
        for (int j = 0; j < NH2; ++j) c = fmaf(sU[j], b1[j], c);
        wsf[WS_CB] = c;
    }
}

// ---------------- main: 32 rows/wave, 2 tiles, ONE shared A-buffer per tile ----------------
// Per step per tile: 1 ds_read_b128 feeds 4 L2(t)-MFMAs AND 4 L1(t+1)-MFMAs
// (B-frags mask the unused k-slots). h1n written once (k=u), h2n once (k=17+u).
// u==15 lanes: UPD1 write hits k15 (x slot) then x(t+1) store fixes it; UPD2 write
// lands at k=32 (pad) — both naturally safe, no redirect.
__global__ __launch_bounds__(256)
void lstm_mfma(const float* __restrict__ x, const float* __restrict__ wsf,
               float* __restrict__ out, int B)
{
    __shared__ __align__(16) _Float16 lds[4][2][16][40];   // [wave][tile][row][k] 10240 B

    const int tid = threadIdx.x;
    const int wid = tid >> 6;
    const int l   = tid & 63;
    const int u   = l & 15;      // A-row / D-col (unit)
    const int g   = l >> 4;
    const int wbase = (blockIdx.x * 4 + wid) * 32;

    // zero EXACTLY this wave's 2 tiles: 2*16*40 halves = 2560 B = 640 dwords
    // (round 12 bug: 20 iterations overran into the next wave's region -> race
    // on graph replay; 10 x 64 lanes x 4 B = 2560 B = own region, pads included)
    {
        unsigned* zw = (unsigned*)&lds[wid][0][0][0];
        #pragma unroll
        for (int i = 0; i < 10; ++i) zw[l + 64 * i] = 0u;
    }

    // load shared B-frags (held in registers for the whole kernel)
    const uint4* wsq = (const uint4*)wsf;
    union FU { uint4 q; f16x8 h; };
#define LOADB(name, fidx) f16x8 name; { FU t_; t_.q = wsq[(fidx) * 64 + l]; name = t_.h; }
    LOADB(B0, 0) LOADB(B1, 1) LOADB(B2, 2) LOADB(B3, 3)
    LOADB(B4, 4) LOADB(B5, 5) LOADB(B6, 6) LOADB(B7, 7)
#undef LOADB

    // x: lane l<32 owns batch row wbase+l (tile til, in-tile row l&15)
    const int til = (l >> 4) & 1;
    const float* xp = x + (size_t)(wbase + (l & 31)) * TT;

    // const 1.0 slot (k16) + x(0) (k15), per tile row
    if (l < 32) {
        lds[wid][til][u][16] = (_Float16)1.0f;
        lds[wid][til][u][15] = (_Float16)xp[0];
    }

    const float cb = wsf[WS_CB];
    f32x4 accA = {cb, cb, cb, cb}, accB = accA;
    f32x4 c1A = {0.f,0.f,0.f,0.f}, c2A = c1A, c1B = c1A, c2B = c1A;  // scaled: c' = 2log2e*c
    const f32x4 zc = {0.f,0.f,0.f,0.f};

#define MFMA(a, b, c) __builtin_amdgcn_mfma_f32_16x16x32_f16((a), (b), (c), 0, 0, 0)

    // fused activation, scaled-c' form: 5 exp2 + 2 rcp per unit-update.
    // c'_new = [c'_old*dn1 + L2E2(eg-1)*dn2] / (dn1*dn2), dn1=(1+ei)(eg+1), dn2=1+ef
    // h = (ec-1)/((1+eo)(ec+1)), ec = exp2(c'_new) = e^{2c}
#define UPDC(i, d0, d1, d2, d3, Cst) \
        const float ei = fast_exp2(-d0[i]); \
        const float ef = fast_exp2(-d1[i]); \
        const float eg = fast_exp2(d2[i]); \
        const float eo = fast_exp2(-d3[i]); \
        const float dn1 = (1.0f + ei) * (eg + 1.0f); \
        const float dn2 = 1.0f + ef; \
        const float t1 = fmaf(L2E2, eg, -L2E2); \
        const float r  = fast_rcp(dn1 * dn2); \
        const float cc = fmaf(Cst[i], dn1, t1 * dn2) * r; \
        Cst[i] = cc; \
        const float ec = fast_exp2(cc); \
        const float hh = (ec - 1.0f) * fast_rcp((1.0f + eo) * (ec + 1.0f));

    // h1n -> k=u (u==15 hits x slot, rewritten by x(t+1) store before the read)
#define UPD1(i, T, Cst, d0, d1, d2, d3) { \
        UPDC(i, d0, d1, d2, d3, Cst) \
        lds[wid][T][4 * g + (i)][u] = (_Float16)hh; }

    // h2n -> k=17+u (u==15 -> k32 pad, harmless)
#define UPD2(i, T, Cst, Acc, e0, e1, e2, e3) { \
        UPDC(i, e0, e1, e2, e3, Cst) \
        lds[wid][T][4 * g + (i)][17 + u] = (_Float16)hh; \
        Acc[i] = fmaf(hh, vt, Acc[i]); }

    // UPD2 for the last step: no h2n store needed
#define UPD2L(i, T, Cst, Acc, e0, e1, e2, e3) { \
        UPDC(i, e0, e1, e2, e3, Cst) \
        Acc[i] = fmaf(hh, vt, Acc[i]); }

    // ---- prologue: L1 MFMAs for t=0 (buffer: h1=0, x0, 1, h2=0) ----
    f16x8 aA = *(const f16x8*)&lds[wid][0][u][g * 8];
    f16x8 aB = *(const f16x8*)&lds[wid][1][u][g * 8];
    f32x4 dA0 = MFMA(aA, B0, zc), dA1 = MFMA(aA, B1, zc);
    f32x4 dA2 = MFMA(aA, B2, zc), dA3 = MFMA(aA, B3, zc);
    f32x4 dB0 = MFMA(aB, B0, zc), dB1 = MFMA(aB, B1, zc);
    f32x4 dB2 = MFMA(aB, B2, zc), dB3 = MFMA(aB, B3, zc);

    #pragma unroll 2
    for (int t = 0; t < TT - 1; ++t) {
        const float xn = xp[t + 1];   // prefetch next x

        // finish layer 1 of step t: h1n -> k0-14 (and u15 lane's stray k15 write)
        UPD1(0, 0, c1A, dA0, dA1, dA2, dA3) UPD1(1, 0, c1A, dA0, dA1, dA2, dA3)
        UPD1(2, 0, c1A, dA0, dA1, dA2, dA3) UPD1(3, 0, c1A, dA0, dA1, dA2, dA3)
        UPD1(0, 1, c1B, dB0, dB1, dB2, dB3) UPD1(1, 1, c1B, dB0, dB1, dB2, dB3)
        UPD1(2, 1, c1B, dB0, dB1, dB2, dB3) UPD1(3, 1, c1B, dB0, dB1, dB2, dB3)

        // x(t+1) into k15 (also repairs u15's stray write)
        if (l < 32) lds[wid][til][u][15] = (_Float16)xn;

        // ONE read per tile: row now holds [h1n(t) | x(t+1) | 1 | h2(t-1)]
        aA = *(const f16x8*)&lds[wid][0][u][g * 8];
        aB = *(const f16x8*)&lds[wid][1][u][g * 8];

        // L2(t): masks x slot, uses h1n(t)+bias1+h2(t-1)
        f32x4 eA0 = MFMA(aA, B4, zc), eA1 = MFMA(aA, B5, zc);
        f32x4 eA2 = MFMA(aA, B6, zc), eA3 = MFMA(aA, B7, zc);
        f32x4 eB0 = MFMA(aB, B4, zc), eB1 = MFMA(aB, B5, zc);
        f32x4 eB2 = MFMA(aB, B6, zc), eB3 = MFMA(aB, B7, zc);
        // L1(t+1): masks h2 region, uses h1n(t)+x(t+1)+bias0
        dA0 = MFMA(aA, B0, zc); dA1 = MFMA(aA, B1, zc);
        dA2 = MFMA(aA, B2, zc); dA3 = MFMA(aA, B3, zc);
        dB0 = MFMA(aB, B0, zc); dB1 = MFMA(aB, B1, zc);
        dB2 = MFMA(aB, B2, zc); dB3 = MFMA(aB, B3, zc);

        // finish layer 2 of step t: h2n(t) -> k17-31 (read next iteration)
        const float vt = wsf[WS_V + t];
        UPD2(0, 0, c2A, accA, eA0, eA1, eA2, eA3) UPD2(1, 0, c2A, accA, eA0, eA1, eA2, eA3)
        UPD2(2, 0, c2A, accA, eA0, eA1, eA2, eA3) UPD2(3, 0, c2A, accA, eA0, eA1, eA2, eA3)
        UPD2(0, 1, c2B, accB, eB0, eB1, eB2, eB3) UPD2(1, 1, c2B, accB, eB0, eB1, eB2, eB3)
        UPD2(2, 1, c2B, accB, eB0, eB1, eB2, eB3) UPD2(3, 1, c2B, accB, eB0, eB1, eB2, eB3)
    }

    // ---- epilogue: t = 14 (no x(15), L2 masks stale k15; no h2n store) ----
    {
        UPD1(0, 0, c1A, dA0, dA1, dA2, dA3) UPD1(1, 0, c1A, dA0, dA1, dA2, dA3)
        UPD1(2, 0, c1A, dA0, dA1, dA2, dA3) UPD1(3, 0, c1A, dA0, dA1, dA2, dA3)
        UPD1(0, 1, c1B, dB0, dB1, dB2, dB3) UPD1(1, 1, c1B, dB0, dB1, dB2, dB3)
        UPD1(2, 1, c1B, dB0, dB1, dB2, dB3) UPD1(3, 1, c1B, dB0, dB1, dB2, dB3)

        aA = *(const f16x8*)&lds[wid][0][u][g * 8];
        aB = *(const f16x8*)&lds[wid][1][u][g * 8];
        f32x4 eA0 = MFMA(aA, B4, zc), eA1 = MFMA(aA, B5, zc);
        f32x4 eA2 = MFMA(aA, B6, zc), eA3 = MFMA(aA, B7, zc);
        f32x4 eB0 = MFMA(aB, B4, zc), eB1 = MFMA(aB, B5, zc);
        f32x4 eB2 = MFMA(aB, B6, zc), eB3 = MFMA(aB, B7, zc);

        const float vt = wsf[WS_V + (TT - 1)];
        UPD2L(0, 0, c2A, accA, eA0, eA1, eA2, eA3) UPD2L(1, 0, c2A, accA, eA0, eA1, eA2, eA3)
        UPD2L(2, 0, c2A, accA, eA0, eA1, eA2, eA3) UPD2L(3, 0, c2A, accA, eA0, eA1, eA2, eA3)
        UPD2L(0, 1, c2B, accB, eB0, eB1, eB2, eB3) UPD2L(1, 1, c2B, accB, eB0, eB1, eB2, eB3)
        UPD2L(2, 1, c2B, accB, eB0, eB1, eB2, eB3) UPD2L(3, 1, c2B, accB, eB0, eB1, eB2, eB3)
    }
#undef UPD1
#undef UPD2
#undef UPD2L
#undef UPDC
#undef MFMA

    // feat = h2[:, :, 14]: unit-14 lanes hold rows 4g..4g+3 of each tile
    if (u == 14) {
        out[wbase + 4 * g + 0] = accA[0];
        out[wbase + 4 * g + 1] = accA[1];
        out[wbase + 4 * g + 2] = accA[2];
        out[wbase + 4 * g + 3] = accA[3];
        out[wbase + 16 + 4 * g + 0] = accB[0];
        out[wbase + 16 + 4 * g + 1] = accB[1];
        out[wbase + 16 + 4 * g + 2] = accB[2];
        out[wbase + 16 + 4 * g + 3] = accB[3];
    }
}

extern "C" void kernel_launch(void* const* d_in, const int* in_sizes, int n_in,
                              void* d_out, int out_size, void* d_ws, size_t ws_size,
                              hipStream_t stream) {
    (void)n_in; (void)ws_size; (void)out_size;
    const float* x    = (const float*)d_in[0];
    const float* Wih0 = (const float*)d_in[1];
    const float* Whh0 = (const float*)d_in[2];
    const float* bih0 = (const float*)d_in[3];
    const float* bhh0 = (const float*)d_in[4];
    const float* Wih1 = (const float*)d_in[5];
    const float* Whh1 = (const float*)d_in[6];
    const float* bih1 = (const float*)d_in[7];
    const float* bhh1 = (const float*)d_in[8];
    const float* W1   = (const float*)d_in[9];
    const float* b1   = (const float*)d_in[10];
    const float* W2   = (const float*)d_in[11];
    const float* b2   = (const float*)d_in[12];
    const float* W3   = (const float*)d_in[13];
    const float* b3   = (const float*)d_in[14];
    float* out = (float*)d_out;
    float* wsf = (float*)d_ws;

    const int B = in_sizes[0] / TT;   // 131072

    lstm_prep<<<1, 512, 0, stream>>>(Wih0, Whh0, bih0, bhh0,
                                     Wih1, Whh1, bih1, bhh1,
                                     W1, b1, W2, b2, W3, b3, wsf);

    // 32 rows per wave (2 tiles), 4 waves per block -> 1024 blocks = 4 blocks/CU
    const int grid = B / (32 * 4);
    lstm_mfma<<<grid, 256, 0, stream>>>(x, wsf, out, B);
}